// Round 16
// baseline (137.543 us; speedup 1.0000x reference)
//
#include <hip/hip_runtime.h>
#include <math.h>

#define HP 258
#define RPAD 320
#define BSTR 328              // bf16 row stride (656B, 16B-aligned)
#define NPIX (HP*HP)
#define NPB  (RPAD*BSTR)
#define PTOT (RPAD*BSTR)
#define C30 30
#define TOT (C30*NPIX)
#define LOGW 64
#define PBLK 410
#define CH 10                 // channels per buildall block (3 chunks)

typedef __bf16 bf16x8 __attribute__((ext_vector_type(8)));
typedef float  f32x4  __attribute__((ext_vector_type(4)));
typedef unsigned short ushort;
typedef unsigned short ushort8 __attribute__((ext_vector_type(8)));

static __device__ inline ushort f2bf(float f){
  __bf16 h = (__bf16)f;
  return __builtin_bit_cast(ushort, h);
}
static __device__ inline float bf2f(ushort u){
  return (float)__builtin_bit_cast(__bf16, u);
}

// ---- bijective XCD swizzle (m204): hardware id -> work id ------------------
static __device__ inline int xcd_swz(int orig, int nwg){
  int xcd = orig & 7, s = orig >> 3;
  int q = nwg >> 3, r = nwg & 7;
  return (xcd < r ? xcd*(q+1) : r*(q+1) + (xcd - r)*q) + s;
}

// paired store variant: two A-tiles (As1, As2) share b0/b1 from one Bs
#define MM_MFMA_PAIR(KK)                                                       \
  {                                                                            \
    bf16x8 b0 = __builtin_bit_cast(bf16x8, *(const ushort8*)(&Bs[(wc      + l15)*72 + (KK) + lq*8])); \
    bf16x8 b1 = __builtin_bit_cast(bf16x8, *(const ushort8*)(&Bs[(wc + 16 + l15)*72 + (KK) + lq*8])); \
    bf16x8 a0 = __builtin_bit_cast(bf16x8, *(const ushort8*)(&As1[(wr      + l15)*72 + (KK) + lq*8])); \
    bf16x8 a1 = __builtin_bit_cast(bf16x8, *(const ushort8*)(&As1[(wr + 16 + l15)*72 + (KK) + lq*8])); \
    p00 = __builtin_amdgcn_mfma_f32_16x16x32_bf16(a0, b0, p00, 0, 0, 0);       \
    p01 = __builtin_amdgcn_mfma_f32_16x16x32_bf16(a0, b1, p01, 0, 0, 0);       \
    p10 = __builtin_amdgcn_mfma_f32_16x16x32_bf16(a1, b0, p10, 0, 0, 0);       \
    p11 = __builtin_amdgcn_mfma_f32_16x16x32_bf16(a1, b1, p11, 0, 0, 0);       \
    a0 = __builtin_bit_cast(bf16x8, *(const ushort8*)(&As2[(wr      + l15)*72 + (KK) + lq*8])); \
    a1 = __builtin_bit_cast(bf16x8, *(const ushort8*)(&As2[(wr + 16 + l15)*72 + (KK) + lq*8])); \
    q00 = __builtin_amdgcn_mfma_f32_16x16x32_bf16(a0, b0, q00, 0, 0, 0);       \
    q01 = __builtin_amdgcn_mfma_f32_16x16x32_bf16(a0, b1, q01, 0, 0, 0);       \
    q10 = __builtin_amdgcn_mfma_f32_16x16x32_bf16(a1, b0, q10, 0, 0, 0);       \
    q11 = __builtin_amdgcn_mfma_f32_16x16x32_bf16(a1, b1, q11, 0, 0, 0);       \
  }

// paired absred variant: p uses BsN (negated/opening), q uses BsP (plain/dil)
#define MM_MFMA_ABSPAIR(KK)                                                    \
  {                                                                            \
    bf16x8 b0 = __builtin_bit_cast(bf16x8, *(const ushort8*)(&BsN[(wc      + l15)*72 + (KK) + lq*8])); \
    bf16x8 b1 = __builtin_bit_cast(bf16x8, *(const ushort8*)(&BsN[(wc + 16 + l15)*72 + (KK) + lq*8])); \
    bf16x8 a0 = __builtin_bit_cast(bf16x8, *(const ushort8*)(&As1[(wr      + l15)*72 + (KK) + lq*8])); \
    bf16x8 a1 = __builtin_bit_cast(bf16x8, *(const ushort8*)(&As1[(wr + 16 + l15)*72 + (KK) + lq*8])); \
    p00 = __builtin_amdgcn_mfma_f32_16x16x32_bf16(a0, b0, p00, 0, 0, 0);       \
    p01 = __builtin_amdgcn_mfma_f32_16x16x32_bf16(a0, b1, p01, 0, 0, 0);       \
    p10 = __builtin_amdgcn_mfma_f32_16x16x32_bf16(a1, b0, p10, 0, 0, 0);       \
    p11 = __builtin_amdgcn_mfma_f32_16x16x32_bf16(a1, b1, p11, 0, 0, 0);       \
    b0 = __builtin_bit_cast(bf16x8, *(const ushort8*)(&BsP[(wc      + l15)*72 + (KK) + lq*8])); \
    b1 = __builtin_bit_cast(bf16x8, *(const ushort8*)(&BsP[(wc + 16 + l15)*72 + (KK) + lq*8])); \
    a0 = __builtin_bit_cast(bf16x8, *(const ushort8*)(&As2[(wr      + l15)*72 + (KK) + lq*8])); \
    a1 = __builtin_bit_cast(bf16x8, *(const ushort8*)(&As2[(wr + 16 + l15)*72 + (KK) + lq*8])); \
    q00 = __builtin_amdgcn_mfma_f32_16x16x32_bf16(a0, b0, q00, 0, 0, 0);       \
    q01 = __builtin_amdgcn_mfma_f32_16x16x32_bf16(a0, b1, q01, 0, 0, 0);       \
    q10 = __builtin_amdgcn_mfma_f32_16x16x32_bf16(a1, b0, q10, 0, 0, 0);       \
    q11 = __builtin_amdgcn_mfma_f32_16x16x32_bf16(a1, b1, q11, 0, 0, 0);       \
  }

// ---- paired mm store: C1 = Aop@B^T (bf16 dense if C1BF), C2 = Adil@B^T -----
template<int C1BF>
static __device__ inline void mm_pair_body(const ushort* __restrict__ A1b,
                                           const ushort* __restrict__ A2b,
                                           const ushort* __restrict__ Bb0,
                                           void* __restrict__ C1v,
                                           float* __restrict__ C2b,
                                           int bx, int by, int tid,
                                           ushort* As1, ushort* As2, ushort* Bs){
  int lane = tid & 63, wv = tid >> 6;
  int wr = (wv >> 1)*32, wc = (wv & 1)*32;
  int rowBase = bx*64, colBase = by*64;
  int l15 = lane & 15, lq = lane >> 4;
  f32x4 p00 = {0.f,0.f,0.f,0.f}, p01 = p00, p10 = p00, p11 = p00;
  f32x4 q00 = p00, q01 = p00, q10 = p00, q11 = p00;
  int srow = tid >> 3, sc8 = tid & 7;
  const ushort* A1 = A1b + (size_t)rowBase*BSTR;
  const ushort* A2 = A2b + (size_t)rowBase*BSTR;
  const ushort* Bb = Bb0 + (size_t)colBase*BSTR;
  const ushort* a1p = A1 + (size_t)srow*BSTR + sc8*8;
  const ushort* a2p = A2 + (size_t)srow*BSTR + sc8*8;
  const ushort* bpt = Bb + (size_t)srow*BSTR + sc8*8;
  for (int k0 = 0; k0 < 256; k0 += 64){
    *(ushort8*)(&As1[srow*72 + sc8*8])      = *(const ushort8*)(a1p + k0);
    *(ushort8*)(&As1[(srow+32)*72 + sc8*8]) = *(const ushort8*)(a1p + (size_t)32*BSTR + k0);
    *(ushort8*)(&As2[srow*72 + sc8*8])      = *(const ushort8*)(a2p + k0);
    *(ushort8*)(&As2[(srow+32)*72 + sc8*8]) = *(const ushort8*)(a2p + (size_t)32*BSTR + k0);
    *(ushort8*)(&Bs[srow*72 + sc8*8])       = *(const ushort8*)(bpt + k0);
    *(ushort8*)(&Bs[(srow+32)*72 + sc8*8])  = *(const ushort8*)(bpt + (size_t)32*BSTR + k0);
    __syncthreads();
    MM_MFMA_PAIR(0);
    MM_MFMA_PAIR(32);
    __syncthreads();
  }
  {  // tail k=256..287 (zero pad beyond 258)
    int row4 = tid >> 2, c84 = tid & 3;
    *(ushort8*)(&As1[row4*72 + c84*8]) = *(const ushort8*)(A1 + (size_t)row4*BSTR + 256 + c84*8);
    *(ushort8*)(&As2[row4*72 + c84*8]) = *(const ushort8*)(A2 + (size_t)row4*BSTR + 256 + c84*8);
    *(ushort8*)(&Bs[row4*72 + c84*8])  = *(const ushort8*)(Bb + (size_t)row4*BSTR + 256 + c84*8);
    __syncthreads();
    MM_MFMA_PAIR(0);
  }
  auto store1 = [&](f32x4 v, int r0, int c0){
    if (c0 < HP){
      #pragma unroll
      for (int r=0;r<4;r++){
        int rr = r0 + r;
        if (rr < HP){
          if (C1BF) ((ushort*)C1v)[(size_t)rr*HP + c0] = f2bf(v[r]);
          else      ((float*)C1v)[(size_t)rr*HP + c0] = v[r];
        }
      }
    }
  };
  auto store2 = [&](f32x4 v, int r0, int c0){
    if (c0 < HP){
      #pragma unroll
      for (int r=0;r<4;r++){
        int rr = r0 + r;
        if (rr < HP) C2b[(size_t)rr*HP + c0] = v[r];
      }
    }
  };
  store1(p00, rowBase + wr +      lq*4, colBase + wc +      l15);
  store1(p01, rowBase + wr +      lq*4, colBase + wc + 16 + l15);
  store1(p10, rowBase + wr + 16 + lq*4, colBase + wc +      l15);
  store1(p11, rowBase + wr + 16 + lq*4, colBase + wc + 16 + l15);
  store2(q00, rowBase + wr +      lq*4, colBase + wc +      l15);
  store2(q01, rowBase + wr +      lq*4, colBase + wc + 16 + l15);
  store2(q10, rowBase + wr + 16 + lq*4, colBase + wc +      l15);
  store2(q11, rowBase + wr + 16 + lq*4, colBase + wc + 16 + l15);
}

// ---- paired mm absred: opening (A1@(-B)) and dilation (A2@B), B read once --
static __device__ inline void mm_abs_pair_body(const ushort* __restrict__ A1b,
                                               const ushort* __restrict__ A2b,
                                               const ushort* __restrict__ Bb0,
                                               const float* __restrict__ Ob,
                                               double* __restrict__ slot_op,
                                               double* __restrict__ slot_dil,
                                               int bx, int by, int tid,
                                               ushort* As1, ushort* As2,
                                               ushort* BsP, ushort* BsN, double* red){
  int lane = tid & 63, wv = tid >> 6;
  int wr = (wv >> 1)*32, wc = (wv & 1)*32;
  int rowBase = bx*64, colBase = by*64;
  int l15 = lane & 15, lq = lane >> 4;
  f32x4 p00 = {0.f,0.f,0.f,0.f}, p01 = p00, p10 = p00, p11 = p00;
  f32x4 q00 = p00, q01 = p00, q10 = p00, q11 = p00;
  int srow = tid >> 3, sc8 = tid & 7;
  const ushort* A1 = A1b + (size_t)rowBase*BSTR;
  const ushort* A2 = A2b + (size_t)rowBase*BSTR;
  const ushort* Bb = Bb0 + (size_t)colBase*BSTR;
  const ushort* a1p = A1 + (size_t)srow*BSTR + sc8*8;
  const ushort* a2p = A2 + (size_t)srow*BSTR + sc8*8;
  const ushort* bpt = Bb + (size_t)srow*BSTR + sc8*8;
  ushort one = f2bf(1.0f);
  auto fixB = [&](ushort8 t8, int brow, int kbase)->ushort8{
    if (brow >= HP) return t8;
    #pragma unroll
    for (int i=0;i<8;i++){
      int kk = kbase + i;
      if (kk < HP)
        t8[i] = (brow==0 || brow==HP-1 || kk==0 || kk==HP-1) ? one : (ushort)(t8[i] ^ 0x8000);
    }
    return t8;
  };
  for (int k0 = 0; k0 < 256; k0 += 64){
    *(ushort8*)(&As1[srow*72 + sc8*8])      = *(const ushort8*)(a1p + k0);
    *(ushort8*)(&As1[(srow+32)*72 + sc8*8]) = *(const ushort8*)(a1p + (size_t)32*BSTR + k0);
    *(ushort8*)(&As2[srow*72 + sc8*8])      = *(const ushort8*)(a2p + k0);
    *(ushort8*)(&As2[(srow+32)*72 + sc8*8]) = *(const ushort8*)(a2p + (size_t)32*BSTR + k0);
    {
      ushort8 t0 = *(const ushort8*)(bpt + k0);
      ushort8 t1 = *(const ushort8*)(bpt + (size_t)32*BSTR + k0);
      *(ushort8*)(&BsP[srow*72 + sc8*8])      = t0;
      *(ushort8*)(&BsP[(srow+32)*72 + sc8*8]) = t1;
      *(ushort8*)(&BsN[srow*72 + sc8*8])      = fixB(t0, colBase + srow,      k0 + sc8*8);
      *(ushort8*)(&BsN[(srow+32)*72 + sc8*8]) = fixB(t1, colBase + srow + 32, k0 + sc8*8);
    }
    __syncthreads();
    MM_MFMA_ABSPAIR(0);
    MM_MFMA_ABSPAIR(32);
    __syncthreads();
  }
  {
    int row4 = tid >> 2, c84 = tid & 3;
    *(ushort8*)(&As1[row4*72 + c84*8]) = *(const ushort8*)(A1 + (size_t)row4*BSTR + 256 + c84*8);
    *(ushort8*)(&As2[row4*72 + c84*8]) = *(const ushort8*)(A2 + (size_t)row4*BSTR + 256 + c84*8);
    ushort8 t0 = *(const ushort8*)(Bb + (size_t)row4*BSTR + 256 + c84*8);
    *(ushort8*)(&BsP[row4*72 + c84*8]) = t0;
    *(ushort8*)(&BsN[row4*72 + c84*8]) = fixB(t0, colBase + row4, 256 + c84*8);
    __syncthreads();
    MM_MFMA_ABSPAIR(0);
  }
  double lop = 0.0, ldl = 0.0;
  auto addq = [&](f32x4 vp, f32x4 vq, int r0, int c0){
    if (c0 < HP){
      #pragma unroll
      for (int r=0;r<4;r++){
        int rr = r0 + r;
        if (rr < HP){
          float o = Ob[(size_t)rr*HP + c0];
          float oo = (rr==0||rr==HP-1||c0==0||c0==HP-1) ? 1.0f : -o;
          lop += (double)fabsf(oo - vp[r]);
          ldl += (double)fabsf(o  - vq[r]);
        }
      }
    }
  };
  addq(p00, q00, rowBase + wr +      lq*4, colBase + wc +      l15);
  addq(p01, q01, rowBase + wr +      lq*4, colBase + wc + 16 + l15);
  addq(p10, q10, rowBase + wr + 16 + lq*4, colBase + wc +      l15);
  addq(p11, q11, rowBase + wr + 16 + lq*4, colBase + wc + 16 + l15);
  red[tid] = lop;
  __syncthreads();
  for (int s=128; s>0; s>>=1){ if (tid<s) red[tid]+=red[tid+s]; __syncthreads(); }
  if (tid==0) *slot_op = red[0];
  __syncthreads();
  red[tid] = ldl;
  __syncthreads();
  for (int s=128; s>0; s>>=1){ if (tid<s) red[tid]+=red[tid+s]; __syncthreads(); }
  if (tid==0) *slot_dil = red[0];
}

// ---- cm matvec: cm = ((colsum A)@XP - colsum x)/258 ------------------------
static __device__ inline void cm_body(int ch, const float* __restrict__ apart_,
                                      const float* __restrict__ xpart_,
                                      const float* __restrict__ XPd,
                                      float* __restrict__ cmo,
                                      float* colA, int tid){
  const float* ap = apart_ + (size_t)ch*10*320;
  for (int k = tid; k < HP; k += 256){
    float s = 0.0f;
    #pragma unroll
    for (int t=0;t<10;t++) s += ap[t*320 + k];
    colA[k] = s;
  }
  __syncthreads();
  const float* xpd = XPd + (size_t)ch*NPIX;
  const float* xp2 = xpart_ + (size_t)ch*10*320;
  for (int w = tid; w < HP; w += 256){
    float acc = 0.0f;
    for (int k=0;k<HP;k++) acc = fmaf(colA[k], xpd[(size_t)k*HP + w], acc);
    float xs = 0.0f;
    #pragma unroll
    for (int t=0;t<10;t++) xs += xp2[t*320 + w];
    cmo[ch*HP + w] = (acc - xs) * (1.0f/(float)HP);
  }
}

// ---- buildall: softmax once per tile, CH=10 channels per block -------------
__global__ __launch_bounds__(256) void fb_buildall_k(const float* __restrict__ logits,
    float* __restrict__ XP, ushort* __restrict__ BFT,
    ushort* __restrict__ BF1, ushort* __restrict__ BF2,
    float* __restrict__ xpart, float* __restrict__ apart){
  __shared__ float s6[6][34][35];
  __shared__ float fcb[34][35];
  __shared__ ushort tbuf[32][33];
  __shared__ float cr[2][8][33];
  int tile = blockIdx.x, chunk = blockIdx.y;
  int tr = tile/10, tc = tile%10;
  int r0 = tr*32, c0 = tc*32;
  int tid = threadIdx.x;
  for (int idx = tid; idx < 34*34; idx += 256){
    int lr = idx/34, lc = idx%34;
    int h = r0 - 1 + lr, w = c0 - 1 + lc;
    float sv[6];
    if (h >= 1 && h <= 256 && w >= 1 && w <= 256){
      int oh = h-1, ow = w-1;
      float fy = 0.25f*oh - 0.375f;
      float fx = 0.25f*ow - 0.375f;
      float y0f = floorf(fy), x0f = floorf(fx);
      float ty = fy - y0f, tx2 = fx - x0f;
      int y0 = max(0, (int)y0f), y1 = min(LOGW-1, (int)y0f + 1);
      int x0 = max(0, (int)x0f), x1 = min(LOGW-1, (int)x0f + 1);
      float m = -3.402823466e+38f;
      #pragma unroll
      for (int c=0;c<6;c++){
        const float* pl = logits + c*LOGW*LOGW;
        float v00 = pl[y0*LOGW + x0], v01 = pl[y0*LOGW + x1];
        float v10 = pl[y1*LOGW + x0], v11 = pl[y1*LOGW + x1];
        float a = v00 + (v01 - v00)*tx2;
        float b = v10 + (v11 - v10)*tx2;
        float v = a + (b - a)*ty;
        sv[c] = v; m = fmaxf(m, v);
      }
      float sum = 0.0f;
      #pragma unroll
      for (int c=0;c<6;c++){ sv[c] = expf(sv[c]-m); sum += sv[c]; }
      float inv = 1.0f/sum;
      #pragma unroll
      for (int c=0;c<6;c++) sv[c] *= inv;
    } else {
      #pragma unroll
      for (int c=0;c<6;c++) sv[c] = 0.0f;
    }
    #pragma unroll
    for (int c=0;c<6;c++) s6[c][lr][lc] = sv[c];
  }
  __syncthreads();
  int tx = tid & 31, rg = tid >> 5;
  for (int cc=0; cc<CH; cc++){
    int ci = chunk*CH + cc;
    int i = ci/5, r = ci%5;
    int j = r + (r>=i ? 1 : 0);
    for (int idx = tid; idx < 34*34; idx += 256){
      int lr = idx/34, lc = idx%34;
      int h = r0 - 1 + lr, w = c0 - 1 + lc;
      float v;
      if (h < 0 || h >= HP || w < 0 || w >= HP) v = 0.0f;
      else if (h==0 || h==HP-1 || w==0 || w==HP-1) v = 1.0f;
      else v = fmaxf(0.5f*(s6[i][lr][lc] - s6[j][lr][lc]), 0.0f);
      fcb[lr][lc] = v;
    }
    __syncthreads();
    float xs_acc = 0.0f, as_acc = 0.0f;
    #pragma unroll
    for (int kk=0; kk<4; kk++){
      int lrow = rg + 8*kk;
      int h = r0 + lrow, w = c0 + tx;
      int lr = lrow + 1, lc = tx + 1;
      float xpv = fcb[lr][lc];
      ushort pmaxv, pavgv, xbfv;
      if (h >= HP || w >= HP){ pmaxv = 0; pavgv = 0; xbfv = 0; }
      else if (h==0 || h==HP-1 || w==0 || w==HP-1){
        pmaxv = f2bf(1.0f); pavgv = pmaxv; xbfv = pmaxv;
        XP[(size_t)ci*NPIX + (size_t)h*HP + w] = 1.0f;
        xs_acc += 1.0f;
        as_acc += 1.0f;
      } else {
        float mv = -3.402823466e+38f, av = 0.0f;
        #pragma unroll
        for (int dy=-1;dy<=1;dy++)
          #pragma unroll
          for (int dx=-1;dx<=1;dx++){
            float nv = fcb[lr+dy][lc+dx];
            mv = fmaxf(mv, nv); av += nv;
          }
        pmaxv = f2bf(mv);
        pavgv = f2bf(av*(1.0f/9.0f));
        xbfv  = f2bf(xpv);
        XP[(size_t)ci*NPIX + (size_t)h*HP + w] = xpv;
        xs_acc += xpv;
        as_acc += bf2f(pavgv);
      }
      size_t ob = (size_t)ci*NPB + (size_t)h*BSTR + w;
      BF1[ob] = pmaxv;
      BF2[ob] = pavgv;
      tbuf[lrow][tx] = xbfv;
    }
    cr[0][rg][tx] = xs_acc;
    cr[1][rg][tx] = as_acc;
    __syncthreads();
    if (tid < 32){
      float xs = 0.0f, as = 0.0f;
      #pragma unroll
      for (int g=0; g<8; g++){ xs += cr[0][g][tid]; as += cr[1][g][tid]; }
      xpart[((size_t)ci*10 + tr)*320 + c0 + tid] = xs;
      apart[((size_t)ci*10 + tr)*320 + c0 + tid] = as;
    }
    #pragma unroll
    for (int kk=0; kk<4; kk++){
      int a = rg + 8*kk;
      BFT[(size_t)ci*NPB + (size_t)(c0+a)*BSTR + (r0 + tx)] = tbuf[tx][a];
    }
    __syncthreads();
  }
}

// ---- paired mm store + cm: 1D grid 780, XCD-swizzled -----------------------
// C1BF=1: opening output as bf16 dense (mm1); C1BF=0: fp32 (mm2)
template<int C1BF>
__global__ __launch_bounds__(256) void fb_mm_k(const ushort* __restrict__ Aop,
    const ushort* __restrict__ Adil, const ushort* __restrict__ BT,
    void* __restrict__ Cop, float* __restrict__ Cdil,
    const float* __restrict__ XPd, const float* __restrict__ apart_,
    const float* __restrict__ xpart_, float* __restrict__ cmo){
  __shared__ ushort As1[64*72];
  __shared__ ushort As2[64*72];
  __shared__ ushort Bs[64*72];
  int wg = xcd_swz(blockIdx.x, 780);
  if (wg >= 750){
    cm_body(wg - 750, apart_, xpart_, XPd, cmo, (float*)As1, threadIdx.x);
    return;
  }
  int bx = wg % 5, by = (wg/5) % 5, ch = wg/25;
  void* c1 = C1BF ? (void*)((ushort*)Cop + (size_t)ch*NPIX)
                  : (void*)((float*)Cop + (size_t)ch*NPIX);
  mm_pair_body<C1BF>(Aop + (size_t)ch*NPB, Adil + (size_t)ch*NPB, BT + (size_t)ch*NPB,
                     c1, Cdil + (size_t)ch*NPIX,
                     bx, by, threadIdx.x, As1, As2, Bs);
}

// ---- tile-fused poolrect: maxpool(bf16 C1)->BF0 AND rect+avgpool -----------
__global__ __launch_bounds__(256) void fb_poolrect_k(const ushort* __restrict__ F1bf,
    ushort* __restrict__ BF0, const float* __restrict__ XP,
    const float* __restrict__ F2, const float* __restrict__ cm,
    float* __restrict__ X1, ushort* __restrict__ BF2,
    float* __restrict__ x1part, float* __restrict__ a2part){
  __shared__ float rect[34][35];
  __shared__ float cr2[2][8][33];
  int ci = blockIdx.y;
  int tl = blockIdx.x;
  int tcx = tl/10, tty = tl%10;
  int c0 = tcx*32, r0 = tty*32;
  int tid = threadIdx.x;
  int tx = tid & 31, rg = tid >> 5;
  {
    const ushort* fb = F1bf + (size_t)ci*NPIX;
    for (int idx = tid; idx < 34*34; idx += 256){
      int lr = idx/34, lc = idx%34;
      int h = r0 - 1 + lr, w = c0 - 1 + lc;
      rect[lr][lc] = (h >= 0 && h < HP && w >= 0 && w < HP) ? bf2f(fb[(size_t)h*HP + w]) : 0.0f;
    }
    __syncthreads();
    #pragma unroll
    for (int kk=0; kk<4; kk++){
      int lrow = rg + 8*kk;
      int h = r0 + lrow, w = c0 + tx;
      ushort o;
      if (h >= HP || w >= HP) o = 0;
      else if (h==0 || h==HP-1 || w==0 || w==HP-1) o = f2bf(1.0f);
      else {
        // values are already bf16-rounded; max is monotone -> f2bf exact
        float mv = fmaxf(fmaxf(rect[lrow][tx],   rect[lrow][tx+1]),   rect[lrow][tx+2]);
        mv = fmaxf(mv, fmaxf(fmaxf(rect[lrow+1][tx], rect[lrow+1][tx+1]), rect[lrow+1][tx+2]));
        mv = fmaxf(mv, fmaxf(fmaxf(rect[lrow+2][tx], rect[lrow+2][tx+1]), rect[lrow+2][tx+2]));
        o = f2bf(mv);
      }
      BF0[(size_t)ci*NPB + (size_t)h*BSTR + w] = o;
    }
    __syncthreads();
  }
  const float* xb = XP + (size_t)ci*NPIX;
  const float* yb = F2 + (size_t)ci*NPIX;
  for (int idx = tid; idx < 34*34; idx += 256){
    int lr = idx/34, lc = idx%34;
    int h = r0 - 1 + lr, w = c0 - 1 + lc;
    float v = 0.0f;
    if (h >= 0 && h < HP && w >= 0 && w < HP){
      float xv = xb[(size_t)h*HP + w];
      float off = yb[(size_t)h*HP + w] - xv - cm[ci*HP + w];
      v = xv + fmaxf(off, 0.0f);
    }
    rect[lr][lc] = v;
  }
  __syncthreads();
  float xs_acc = 0.0f, as_acc = 0.0f;
  #pragma unroll
  for (int kk=0; kk<4; kk++){
    int lrow = rg + 8*kk;
    int h = r0 + lrow, w = c0 + tx;
    bool vpix = (h < HP && w < HP);
    ushort o;
    if (!vpix) o = 0;
    else {
      float xv = rect[lrow+1][tx+1];
      X1[(size_t)ci*NPIX + (size_t)h*HP + w] = xv;
      xs_acc += xv;
      if (h==0 || h==HP-1 || w==0 || w==HP-1){
        o = f2bf(1.0f);
        as_acc += 1.0f;
      } else {
        float av = (rect[lrow][tx]   + rect[lrow][tx+1]   + rect[lrow][tx+2])
                 + (rect[lrow+1][tx] + rect[lrow+1][tx+1] + rect[lrow+1][tx+2])
                 + (rect[lrow+2][tx] + rect[lrow+2][tx+1] + rect[lrow+2][tx+2]);
        o = f2bf(av*(1.0f/9.0f));
        as_acc += bf2f(o);
      }
    }
    BF2[(size_t)ci*NPB + (size_t)h*BSTR + w] = o;
  }
  cr2[0][rg][tx] = xs_acc;
  cr2[1][rg][tx] = as_acc;
  __syncthreads();
  if (tid < 32){
    float xs = 0.0f, as = 0.0f;
    #pragma unroll
    for (int g=0; g<8; g++){ xs += cr2[0][g][tid]; as += cr2[1][g][tid]; }
    x1part[((size_t)ci*10 + tty)*320 + c0 + tid] = xs;
    a2part[((size_t)ci*10 + tty)*320 + c0 + tid] = as;
  }
}

// ---- invrect (unchanged) ---------------------------------------------------
__global__ __launch_bounds__(256) void fb_invrect_k(const float* __restrict__ F1,
    ushort* __restrict__ An, const float* __restrict__ X1,
    const float* __restrict__ F2, const float* __restrict__ cm,
    ushort* __restrict__ An2){
  bool second = (blockIdx.x >= PBLK);
  int p = (second ? blockIdx.x - PBLK : (int)blockIdx.x)*256 + threadIdx.x;
  if (p >= PTOT) return;
  int h = p / BSTR, w = p % BSTR;
  ushort* dst = second ? An2 : An;
  if (h >= HP || w >= HP){
    #pragma unroll
    for (int c=0;c<C30;c++) dst[(size_t)c*NPB+p] = 0;
    return;
  }
  int pd = h*HP + w;
  float v[C30];
  float ss = 0.0f;
  if (!second){
    #pragma unroll
    for (int c=0;c<C30;c++){ v[c] = F1[(size_t)c*NPIX+pd]; ss = fmaf(v[c],v[c],ss); }
  } else {
    #pragma unroll
    for (int c=0;c<C30;c++){
      float xv = X1[(size_t)c*NPIX + pd];
      float off = F2[(size_t)c*NPIX + pd] - xv - cm[c*HP + w];
      float vv = xv + fmaxf(off, 0.0f);
      v[c] = vv;
      ss = fmaf(vv, vv, ss);
    }
  }
  float n = sqrtf(2.0f*ss);
  float inv = 1.0f / fmaxf(n, 1e-12f);
  #pragma unroll
  for (int c=0;c<C30;c++) dst[(size_t)c*NPB+p] = f2bf(v[c]*inv);
}

// ---- paired mm absred: 1D grid 750, XCD-swizzled ---------------------------
__global__ __launch_bounds__(256) void fb_mmabs_k(const ushort* __restrict__ Aop,
    const ushort* __restrict__ Adil, const ushort* __restrict__ BT,
    const float* __restrict__ XPop, double* __restrict__ part){
  __shared__ ushort As1[64*72];
  __shared__ ushort As2[64*72];
  __shared__ ushort BsP[64*72];
  __shared__ ushort BsN[64*72];
  __shared__ double red[256];
  int wg = xcd_swz(blockIdx.x, 750);
  int bx = wg % 5, by = (wg/5) % 5, ch = wg/25;
  int lin = by*5 + bx;
  mm_abs_pair_body(Aop + (size_t)ch*NPB, Adil + (size_t)ch*NPB, BT + (size_t)ch*NPB,
                   XPop + (size_t)ch*NPIX,
                   &part[(size_t)ch*25 + lin],
                   &part[(size_t)(C30+ch)*25 + lin],
                   bx, by, threadIdx.x, As1, As2, BsP, BsN, red);
}

__global__ void fb_finalize_k(const double* __restrict__ part,
                              const float* __restrict__ base, float* __restrict__ out){
  __shared__ double s0[256], s1[256];
  int tid = threadIdx.x;
  double l0=0.0, l1=0.0;
  for (int i=tid;i<750;i+=256){ l0 += part[i]; l1 += part[750+i]; }
  s0[tid]=l0; s1[tid]=l1; __syncthreads();
  for (int s=128;s>0;s>>=1){ if (tid<s){ s0[tid]+=s0[tid+s]; s1[tid]+=s1[tid+s]; } __syncthreads(); }
  if (tid==0) out[0] = (float)(fabs(2.0*(s0[0]-s1[0])) + (double)base[0]);
}

extern "C" void kernel_launch(void* const* d_in, const int* in_sizes, int n_in,
                              void* d_out, int out_size, void* d_ws, size_t ws_size,
                              hipStream_t stream){
  const float* logits = (const float*)d_in[0];
  const float* base   = (const float*)d_in[1];
  float* out = (float*)d_out;

  char* ws = (char*)d_ws;
  size_t off = 0;
  auto alloc = [&](size_t bytes)->char*{
    char* p = ws + off; off = (off + bytes + 255) & ~(size_t)255; return p;
  };
  double* part    = (double*)alloc(1500*sizeof(double));
  float*  cm      = (float*) alloc((size_t)C30*HP*sizeof(float));
  float*  xpart   = (float*) alloc((size_t)C30*10*320*sizeof(float));
  float*  apart   = (float*) alloc((size_t)C30*10*320*sizeof(float));
  float*  x1part  = (float*) alloc((size_t)C30*10*320*sizeof(float));
  float*  a2part  = (float*) alloc((size_t)C30*10*320*sizeof(float));
  float*  XP      = (float*) alloc((size_t)TOT*sizeof(float));
  ushort* BF0     = (ushort*)alloc((size_t)C30*NPB*sizeof(ushort));
  ushort* BFT     = (ushort*)alloc((size_t)C30*NPB*sizeof(ushort));
  ushort* BF1     = (ushort*)alloc((size_t)C30*NPB*sizeof(ushort));
  ushort* BF2     = (ushort*)alloc((size_t)C30*NPB*sizeof(ushort));
  ushort* F1bf    = (ushort*)alloc((size_t)TOT*sizeof(ushort));   // opening C1 (bf16 dense)
  float*  F1      = (float*) alloc((size_t)TOT*sizeof(float));    // opening O2 (fp32)
  float*  F2      = (float*) alloc((size_t)TOT*sizeof(float));
  float*  X1      = (float*) alloc((size_t)TOT*sizeof(float));
  (void)ws_size; (void)in_sizes; (void)n_in; (void)out_size;

  dim3 baGrid(100, 3);
  dim3 prGrid(100, C30);

  fb_buildall_k<<<baGrid,256,0,stream>>>(logits, XP, BFT, BF1, BF2, xpart, apart);
  fb_mm_k<1><<<780,256,0,stream>>>(BF1, BF2, BFT, F1bf, F2, XP, apart, xpart, cm);
  fb_poolrect_k<<<prGrid,256,0,stream>>>(F1bf, BF0, XP, F2, cm, X1, BF2, x1part, a2part);
  fb_mm_k<0><<<780,256,0,stream>>>(BF0, BF2, BFT, F1, F2, XP, a2part, x1part, cm);
  fb_invrect_k<<<820,256,0,stream>>>(F1, BF1, X1, F2, cm, BF0);
  fb_mmabs_k<<<750,256,0,stream>>>(BF1, BF0, BFT, XP, part);
  fb_finalize_k<<<1,256,0,stream>>>(part, base, out);
}

// Round 17
// 129.912 us; speedup vs baseline: 1.0587x; 1.0587x over previous
//
#include <hip/hip_runtime.h>
#include <math.h>

#define HP 258
#define RPAD 320
#define BSTR 328              // bf16 row stride (656B, 16B-aligned)
#define NPIX (HP*HP)
#define NPB  (RPAD*BSTR)
#define PTOT (RPAD*BSTR)
#define C30 30
#define TOT (C30*NPIX)
#define LOGW 64
#define PBLK 410
#define CH 3                  // channels per buildall block (10 chunks)

typedef __bf16 bf16x8 __attribute__((ext_vector_type(8)));
typedef float  f32x4  __attribute__((ext_vector_type(4)));
typedef unsigned short ushort;
typedef unsigned short ushort8 __attribute__((ext_vector_type(8)));

static __device__ inline ushort f2bf(float f){
  __bf16 h = (__bf16)f;
  return __builtin_bit_cast(ushort, h);
}
static __device__ inline float bf2f(ushort u){
  return (float)__builtin_bit_cast(__bf16, u);
}

// ---- bijective XCD swizzle (m204): hardware id -> work id ------------------
static __device__ inline int xcd_swz(int orig, int nwg){
  int xcd = orig & 7, s = orig >> 3;
  int q = nwg >> 3, r = nwg & 7;
  return (xcd < r ? xcd*(q+1) : r*(q+1) + (xcd - r)*q) + s;
}

// paired store variant: two A-tiles (As1, As2) share b0/b1 from one Bs
#define MM_MFMA_PAIR(KK)                                                       \
  {                                                                            \
    bf16x8 b0 = __builtin_bit_cast(bf16x8, *(const ushort8*)(&Bs[(wc      + l15)*72 + (KK) + lq*8])); \
    bf16x8 b1 = __builtin_bit_cast(bf16x8, *(const ushort8*)(&Bs[(wc + 16 + l15)*72 + (KK) + lq*8])); \
    bf16x8 a0 = __builtin_bit_cast(bf16x8, *(const ushort8*)(&As1[(wr      + l15)*72 + (KK) + lq*8])); \
    bf16x8 a1 = __builtin_bit_cast(bf16x8, *(const ushort8*)(&As1[(wr + 16 + l15)*72 + (KK) + lq*8])); \
    p00 = __builtin_amdgcn_mfma_f32_16x16x32_bf16(a0, b0, p00, 0, 0, 0);       \
    p01 = __builtin_amdgcn_mfma_f32_16x16x32_bf16(a0, b1, p01, 0, 0, 0);       \
    p10 = __builtin_amdgcn_mfma_f32_16x16x32_bf16(a1, b0, p10, 0, 0, 0);       \
    p11 = __builtin_amdgcn_mfma_f32_16x16x32_bf16(a1, b1, p11, 0, 0, 0);       \
    a0 = __builtin_bit_cast(bf16x8, *(const ushort8*)(&As2[(wr      + l15)*72 + (KK) + lq*8])); \
    a1 = __builtin_bit_cast(bf16x8, *(const ushort8*)(&As2[(wr + 16 + l15)*72 + (KK) + lq*8])); \
    q00 = __builtin_amdgcn_mfma_f32_16x16x32_bf16(a0, b0, q00, 0, 0, 0);       \
    q01 = __builtin_amdgcn_mfma_f32_16x16x32_bf16(a0, b1, q01, 0, 0, 0);       \
    q10 = __builtin_amdgcn_mfma_f32_16x16x32_bf16(a1, b0, q10, 0, 0, 0);       \
    q11 = __builtin_amdgcn_mfma_f32_16x16x32_bf16(a1, b1, q11, 0, 0, 0);       \
  }

// paired absred variant: p uses BsN (negated/opening), q uses BsP (plain/dil)
#define MM_MFMA_ABSPAIR(KK)                                                    \
  {                                                                            \
    bf16x8 b0 = __builtin_bit_cast(bf16x8, *(const ushort8*)(&BsN[(wc      + l15)*72 + (KK) + lq*8])); \
    bf16x8 b1 = __builtin_bit_cast(bf16x8, *(const ushort8*)(&BsN[(wc + 16 + l15)*72 + (KK) + lq*8])); \
    bf16x8 a0 = __builtin_bit_cast(bf16x8, *(const ushort8*)(&As1[(wr      + l15)*72 + (KK) + lq*8])); \
    bf16x8 a1 = __builtin_bit_cast(bf16x8, *(const ushort8*)(&As1[(wr + 16 + l15)*72 + (KK) + lq*8])); \
    p00 = __builtin_amdgcn_mfma_f32_16x16x32_bf16(a0, b0, p00, 0, 0, 0);       \
    p01 = __builtin_amdgcn_mfma_f32_16x16x32_bf16(a0, b1, p01, 0, 0, 0);       \
    p10 = __builtin_amdgcn_mfma_f32_16x16x32_bf16(a1, b0, p10, 0, 0, 0);       \
    p11 = __builtin_amdgcn_mfma_f32_16x16x32_bf16(a1, b1, p11, 0, 0, 0);       \
    b0 = __builtin_bit_cast(bf16x8, *(const ushort8*)(&BsP[(wc      + l15)*72 + (KK) + lq*8])); \
    b1 = __builtin_bit_cast(bf16x8, *(const ushort8*)(&BsP[(wc + 16 + l15)*72 + (KK) + lq*8])); \
    a0 = __builtin_bit_cast(bf16x8, *(const ushort8*)(&As2[(wr      + l15)*72 + (KK) + lq*8])); \
    a1 = __builtin_bit_cast(bf16x8, *(const ushort8*)(&As2[(wr + 16 + l15)*72 + (KK) + lq*8])); \
    q00 = __builtin_amdgcn_mfma_f32_16x16x32_bf16(a0, b0, q00, 0, 0, 0);       \
    q01 = __builtin_amdgcn_mfma_f32_16x16x32_bf16(a0, b1, q01, 0, 0, 0);       \
    q10 = __builtin_amdgcn_mfma_f32_16x16x32_bf16(a1, b0, q10, 0, 0, 0);       \
    q11 = __builtin_amdgcn_mfma_f32_16x16x32_bf16(a1, b1, q11, 0, 0, 0);       \
  }

// ---- paired mm store: C1 = Aop@B^T (bf16 dense if C1BF), C2 = Adil@B^T -----
template<int C1BF>
static __device__ inline void mm_pair_body(const ushort* __restrict__ A1b,
                                           const ushort* __restrict__ A2b,
                                           const ushort* __restrict__ Bb0,
                                           void* __restrict__ C1v,
                                           float* __restrict__ C2b,
                                           int bx, int by, int tid,
                                           ushort* As1, ushort* As2, ushort* Bs){
  int lane = tid & 63, wv = tid >> 6;
  int wr = (wv >> 1)*32, wc = (wv & 1)*32;
  int rowBase = bx*64, colBase = by*64;
  int l15 = lane & 15, lq = lane >> 4;
  f32x4 p00 = {0.f,0.f,0.f,0.f}, p01 = p00, p10 = p00, p11 = p00;
  f32x4 q00 = p00, q01 = p00, q10 = p00, q11 = p00;
  int srow = tid >> 3, sc8 = tid & 7;
  const ushort* A1 = A1b + (size_t)rowBase*BSTR;
  const ushort* A2 = A2b + (size_t)rowBase*BSTR;
  const ushort* Bb = Bb0 + (size_t)colBase*BSTR;
  const ushort* a1p = A1 + (size_t)srow*BSTR + sc8*8;
  const ushort* a2p = A2 + (size_t)srow*BSTR + sc8*8;
  const ushort* bpt = Bb + (size_t)srow*BSTR + sc8*8;
  for (int k0 = 0; k0 < 256; k0 += 64){
    *(ushort8*)(&As1[srow*72 + sc8*8])      = *(const ushort8*)(a1p + k0);
    *(ushort8*)(&As1[(srow+32)*72 + sc8*8]) = *(const ushort8*)(a1p + (size_t)32*BSTR + k0);
    *(ushort8*)(&As2[srow*72 + sc8*8])      = *(const ushort8*)(a2p + k0);
    *(ushort8*)(&As2[(srow+32)*72 + sc8*8]) = *(const ushort8*)(a2p + (size_t)32*BSTR + k0);
    *(ushort8*)(&Bs[srow*72 + sc8*8])       = *(const ushort8*)(bpt + k0);
    *(ushort8*)(&Bs[(srow+32)*72 + sc8*8])  = *(const ushort8*)(bpt + (size_t)32*BSTR + k0);
    __syncthreads();
    MM_MFMA_PAIR(0);
    MM_MFMA_PAIR(32);
    __syncthreads();
  }
  {  // tail k=256..287 (zero pad beyond 258)
    int row4 = tid >> 2, c84 = tid & 3;
    *(ushort8*)(&As1[row4*72 + c84*8]) = *(const ushort8*)(A1 + (size_t)row4*BSTR + 256 + c84*8);
    *(ushort8*)(&As2[row4*72 + c84*8]) = *(const ushort8*)(A2 + (size_t)row4*BSTR + 256 + c84*8);
    *(ushort8*)(&Bs[row4*72 + c84*8])  = *(const ushort8*)(Bb + (size_t)row4*BSTR + 256 + c84*8);
    __syncthreads();
    MM_MFMA_PAIR(0);
  }
  auto store1 = [&](f32x4 v, int r0, int c0){
    if (c0 < HP){
      #pragma unroll
      for (int r=0;r<4;r++){
        int rr = r0 + r;
        if (rr < HP){
          if (C1BF) ((ushort*)C1v)[(size_t)rr*HP + c0] = f2bf(v[r]);
          else      ((float*)C1v)[(size_t)rr*HP + c0] = v[r];
        }
      }
    }
  };
  auto store2 = [&](f32x4 v, int r0, int c0){
    if (c0 < HP){
      #pragma unroll
      for (int r=0;r<4;r++){
        int rr = r0 + r;
        if (rr < HP) C2b[(size_t)rr*HP + c0] = v[r];
      }
    }
  };
  store1(p00, rowBase + wr +      lq*4, colBase + wc +      l15);
  store1(p01, rowBase + wr +      lq*4, colBase + wc + 16 + l15);
  store1(p10, rowBase + wr + 16 + lq*4, colBase + wc +      l15);
  store1(p11, rowBase + wr + 16 + lq*4, colBase + wc + 16 + l15);
  store2(q00, rowBase + wr +      lq*4, colBase + wc +      l15);
  store2(q01, rowBase + wr +      lq*4, colBase + wc + 16 + l15);
  store2(q10, rowBase + wr + 16 + lq*4, colBase + wc +      l15);
  store2(q11, rowBase + wr + 16 + lq*4, colBase + wc + 16 + l15);
}

// ---- paired mm absred: opening (A1@(-B)) and dilation (A2@B), B read once --
static __device__ inline void mm_abs_pair_body(const ushort* __restrict__ A1b,
                                               const ushort* __restrict__ A2b,
                                               const ushort* __restrict__ Bb0,
                                               const float* __restrict__ Ob,
                                               double* __restrict__ slot_op,
                                               double* __restrict__ slot_dil,
                                               int bx, int by, int tid,
                                               ushort* As1, ushort* As2,
                                               ushort* BsP, ushort* BsN, double* red){
  int lane = tid & 63, wv = tid >> 6;
  int wr = (wv >> 1)*32, wc = (wv & 1)*32;
  int rowBase = bx*64, colBase = by*64;
  int l15 = lane & 15, lq = lane >> 4;
  f32x4 p00 = {0.f,0.f,0.f,0.f}, p01 = p00, p10 = p00, p11 = p00;
  f32x4 q00 = p00, q01 = p00, q10 = p00, q11 = p00;
  int srow = tid >> 3, sc8 = tid & 7;
  const ushort* A1 = A1b + (size_t)rowBase*BSTR;
  const ushort* A2 = A2b + (size_t)rowBase*BSTR;
  const ushort* Bb = Bb0 + (size_t)colBase*BSTR;
  const ushort* a1p = A1 + (size_t)srow*BSTR + sc8*8;
  const ushort* a2p = A2 + (size_t)srow*BSTR + sc8*8;
  const ushort* bpt = Bb + (size_t)srow*BSTR + sc8*8;
  ushort one = f2bf(1.0f);
  auto fixB = [&](ushort8 t8, int brow, int kbase)->ushort8{
    if (brow >= HP) return t8;
    #pragma unroll
    for (int i=0;i<8;i++){
      int kk = kbase + i;
      if (kk < HP)
        t8[i] = (brow==0 || brow==HP-1 || kk==0 || kk==HP-1) ? one : (ushort)(t8[i] ^ 0x8000);
    }
    return t8;
  };
  for (int k0 = 0; k0 < 256; k0 += 64){
    *(ushort8*)(&As1[srow*72 + sc8*8])      = *(const ushort8*)(a1p + k0);
    *(ushort8*)(&As1[(srow+32)*72 + sc8*8]) = *(const ushort8*)(a1p + (size_t)32*BSTR + k0);
    *(ushort8*)(&As2[srow*72 + sc8*8])      = *(const ushort8*)(a2p + k0);
    *(ushort8*)(&As2[(srow+32)*72 + sc8*8]) = *(const ushort8*)(a2p + (size_t)32*BSTR + k0);
    {
      ushort8 t0 = *(const ushort8*)(bpt + k0);
      ushort8 t1 = *(const ushort8*)(bpt + (size_t)32*BSTR + k0);
      *(ushort8*)(&BsP[srow*72 + sc8*8])      = t0;
      *(ushort8*)(&BsP[(srow+32)*72 + sc8*8]) = t1;
      *(ushort8*)(&BsN[srow*72 + sc8*8])      = fixB(t0, colBase + srow,      k0 + sc8*8);
      *(ushort8*)(&BsN[(srow+32)*72 + sc8*8]) = fixB(t1, colBase + srow + 32, k0 + sc8*8);
    }
    __syncthreads();
    MM_MFMA_ABSPAIR(0);
    MM_MFMA_ABSPAIR(32);
    __syncthreads();
  }
  {
    int row4 = tid >> 2, c84 = tid & 3;
    *(ushort8*)(&As1[row4*72 + c84*8]) = *(const ushort8*)(A1 + (size_t)row4*BSTR + 256 + c84*8);
    *(ushort8*)(&As2[row4*72 + c84*8]) = *(const ushort8*)(A2 + (size_t)row4*BSTR + 256 + c84*8);
    ushort8 t0 = *(const ushort8*)(Bb + (size_t)row4*BSTR + 256 + c84*8);
    *(ushort8*)(&BsP[row4*72 + c84*8]) = t0;
    *(ushort8*)(&BsN[row4*72 + c84*8]) = fixB(t0, colBase + row4, 256 + c84*8);
    __syncthreads();
    MM_MFMA_ABSPAIR(0);
  }
  double lop = 0.0, ldl = 0.0;
  auto addq = [&](f32x4 vp, f32x4 vq, int r0, int c0){
    if (c0 < HP){
      #pragma unroll
      for (int r=0;r<4;r++){
        int rr = r0 + r;
        if (rr < HP){
          float o = Ob[(size_t)rr*HP + c0];
          float oo = (rr==0||rr==HP-1||c0==0||c0==HP-1) ? 1.0f : -o;
          lop += (double)fabsf(oo - vp[r]);
          ldl += (double)fabsf(o  - vq[r]);
        }
      }
    }
  };
  addq(p00, q00, rowBase + wr +      lq*4, colBase + wc +      l15);
  addq(p01, q01, rowBase + wr +      lq*4, colBase + wc + 16 + l15);
  addq(p10, q10, rowBase + wr + 16 + lq*4, colBase + wc +      l15);
  addq(p11, q11, rowBase + wr + 16 + lq*4, colBase + wc + 16 + l15);
  red[tid] = lop;
  __syncthreads();
  for (int s=128; s>0; s>>=1){ if (tid<s) red[tid]+=red[tid+s]; __syncthreads(); }
  if (tid==0) *slot_op = red[0];
  __syncthreads();
  red[tid] = ldl;
  __syncthreads();
  for (int s=128; s>0; s>>=1){ if (tid<s) red[tid]+=red[tid+s]; __syncthreads(); }
  if (tid==0) *slot_dil = red[0];
}

// ---- cm matvec: cm = ((colsum A)@XP - colsum x)/258 ------------------------
static __device__ inline void cm_body(int ch, const float* __restrict__ apart_,
                                      const float* __restrict__ xpart_,
                                      const float* __restrict__ XPd,
                                      float* __restrict__ cmo,
                                      float* colA, int tid){
  const float* ap = apart_ + (size_t)ch*10*320;
  for (int k = tid; k < HP; k += 256){
    float s = 0.0f;
    #pragma unroll
    for (int t=0;t<10;t++) s += ap[t*320 + k];
    colA[k] = s;
  }
  __syncthreads();
  const float* xpd = XPd + (size_t)ch*NPIX;
  const float* xp2 = xpart_ + (size_t)ch*10*320;
  for (int w = tid; w < HP; w += 256){
    float acc = 0.0f;
    for (int k=0;k<HP;k++) acc = fmaf(colA[k], xpd[(size_t)k*HP + w], acc);
    float xs = 0.0f;
    #pragma unroll
    for (int t=0;t<10;t++) xs += xp2[t*320 + w];
    cmo[ch*HP + w] = (acc - xs) * (1.0f/(float)HP);
  }
}

// ---- buildall: softmax+fc+XP+BFT+pools+col partials (CH=3, R15-verified) ---
__global__ __launch_bounds__(256) void fb_buildall_k(const float* __restrict__ logits,
    float* __restrict__ XP, ushort* __restrict__ BFT,
    ushort* __restrict__ BF1, ushort* __restrict__ BF2,
    float* __restrict__ xpart, float* __restrict__ apart){
  __shared__ float s6[6][34][35];
  __shared__ float fcb[34][35];
  __shared__ ushort tbuf[32][33];
  __shared__ float cr[2][8][33];
  int tile = blockIdx.x, chunk = blockIdx.y;
  int tr = tile/10, tc = tile%10;
  int r0 = tr*32, c0 = tc*32;
  int tid = threadIdx.x;
  for (int idx = tid; idx < 34*34; idx += 256){
    int lr = idx/34, lc = idx%34;
    int h = r0 - 1 + lr, w = c0 - 1 + lc;
    float sv[6];
    if (h >= 1 && h <= 256 && w >= 1 && w <= 256){
      int oh = h-1, ow = w-1;
      float fy = 0.25f*oh - 0.375f;
      float fx = 0.25f*ow - 0.375f;
      float y0f = floorf(fy), x0f = floorf(fx);
      float ty = fy - y0f, tx2 = fx - x0f;
      int y0 = max(0, (int)y0f), y1 = min(LOGW-1, (int)y0f + 1);
      int x0 = max(0, (int)x0f), x1 = min(LOGW-1, (int)x0f + 1);
      float m = -3.402823466e+38f;
      #pragma unroll
      for (int c=0;c<6;c++){
        const float* pl = logits + c*LOGW*LOGW;
        float v00 = pl[y0*LOGW + x0], v01 = pl[y0*LOGW + x1];
        float v10 = pl[y1*LOGW + x0], v11 = pl[y1*LOGW + x1];
        float a = v00 + (v01 - v00)*tx2;
        float b = v10 + (v11 - v10)*tx2;
        float v = a + (b - a)*ty;
        sv[c] = v; m = fmaxf(m, v);
      }
      float sum = 0.0f;
      #pragma unroll
      for (int c=0;c<6;c++){ sv[c] = expf(sv[c]-m); sum += sv[c]; }
      float inv = 1.0f/sum;
      #pragma unroll
      for (int c=0;c<6;c++) sv[c] *= inv;
    } else {
      #pragma unroll
      for (int c=0;c<6;c++) sv[c] = 0.0f;
    }
    #pragma unroll
    for (int c=0;c<6;c++) s6[c][lr][lc] = sv[c];
  }
  __syncthreads();
  int tx = tid & 31, rg = tid >> 5;
  for (int cc=0; cc<CH; cc++){
    int ci = chunk*CH + cc;
    int i = ci/5, r = ci%5;
    int j = r + (r>=i ? 1 : 0);
    for (int idx = tid; idx < 34*34; idx += 256){
      int lr = idx/34, lc = idx%34;
      int h = r0 - 1 + lr, w = c0 - 1 + lc;
      float v;
      if (h < 0 || h >= HP || w < 0 || w >= HP) v = 0.0f;
      else if (h==0 || h==HP-1 || w==0 || w==HP-1) v = 1.0f;
      else v = fmaxf(0.5f*(s6[i][lr][lc] - s6[j][lr][lc]), 0.0f);
      fcb[lr][lc] = v;
    }
    __syncthreads();
    float xs_acc = 0.0f, as_acc = 0.0f;
    #pragma unroll
    for (int kk=0; kk<4; kk++){
      int lrow = rg + 8*kk;
      int h = r0 + lrow, w = c0 + tx;
      int lr = lrow + 1, lc = tx + 1;
      float xpv = fcb[lr][lc];
      ushort pmaxv, pavgv, xbfv;
      if (h >= HP || w >= HP){ pmaxv = 0; pavgv = 0; xbfv = 0; }
      else if (h==0 || h==HP-1 || w==0 || w==HP-1){
        pmaxv = f2bf(1.0f); pavgv = pmaxv; xbfv = pmaxv;
        XP[(size_t)ci*NPIX + (size_t)h*HP + w] = 1.0f;
        xs_acc += 1.0f;
        as_acc += 1.0f;
      } else {
        float mv = -3.402823466e+38f, av = 0.0f;
        #pragma unroll
        for (int dy=-1;dy<=1;dy++)
          #pragma unroll
          for (int dx=-1;dx<=1;dx++){
            float nv = fcb[lr+dy][lc+dx];
            mv = fmaxf(mv, nv); av += nv;
          }
        pmaxv = f2bf(mv);
        pavgv = f2bf(av*(1.0f/9.0f));
        xbfv  = f2bf(xpv);
        XP[(size_t)ci*NPIX + (size_t)h*HP + w] = xpv;
        xs_acc += xpv;
        as_acc += bf2f(pavgv);
      }
      size_t ob = (size_t)ci*NPB + (size_t)h*BSTR + w;
      BF1[ob] = pmaxv;
      BF2[ob] = pavgv;
      tbuf[lrow][tx] = xbfv;
    }
    cr[0][rg][tx] = xs_acc;
    cr[1][rg][tx] = as_acc;
    __syncthreads();
    if (tid < 32){
      float xs = 0.0f, as = 0.0f;
      #pragma unroll
      for (int g=0; g<8; g++){ xs += cr[0][g][tid]; as += cr[1][g][tid]; }
      xpart[((size_t)ci*10 + tr)*320 + c0 + tid] = xs;
      apart[((size_t)ci*10 + tr)*320 + c0 + tid] = as;
    }
    #pragma unroll
    for (int kk=0; kk<4; kk++){
      int a = rg + 8*kk;
      BFT[(size_t)ci*NPB + (size_t)(c0+a)*BSTR + (r0 + tx)] = tbuf[tx][a];
    }
    __syncthreads();
  }
}

// ---- paired mm store + cm: 1D grid 780, XCD-swizzled -----------------------
template<int C1BF>
__global__ __launch_bounds__(256) void fb_mm_k(const ushort* __restrict__ Aop,
    const ushort* __restrict__ Adil, const ushort* __restrict__ BT,
    void* __restrict__ Cop, float* __restrict__ Cdil,
    const float* __restrict__ XPd, const float* __restrict__ apart_,
    const float* __restrict__ xpart_, float* __restrict__ cmo){
  __shared__ ushort As1[64*72];
  __shared__ ushort As2[64*72];
  __shared__ ushort Bs[64*72];
  int wg = xcd_swz(blockIdx.x, 780);
  if (wg >= 750){
    cm_body(wg - 750, apart_, xpart_, XPd, cmo, (float*)As1, threadIdx.x);
    return;
  }
  int bx = wg % 5, by = (wg/5) % 5, ch = wg/25;
  void* c1 = C1BF ? (void*)((ushort*)Cop + (size_t)ch*NPIX)
                  : (void*)((float*)Cop + (size_t)ch*NPIX);
  mm_pair_body<C1BF>(Aop + (size_t)ch*NPB, Adil + (size_t)ch*NPB, BT + (size_t)ch*NPB,
                     c1, Cdil + (size_t)ch*NPIX,
                     bx, by, threadIdx.x, As1, As2, Bs);
}

// ---- tile-fused poolrect: maxpool(bf16 C1)->BF0 AND rect+avgpool -----------
__global__ __launch_bounds__(256) void fb_poolrect_k(const ushort* __restrict__ F1bf,
    ushort* __restrict__ BF0, const float* __restrict__ XP,
    const float* __restrict__ F2, const float* __restrict__ cm,
    float* __restrict__ X1, ushort* __restrict__ BF2,
    float* __restrict__ x1part, float* __restrict__ a2part){
  __shared__ float rect[34][35];
  __shared__ float cr2[2][8][33];
  int ci = blockIdx.y;
  int tl = blockIdx.x;
  int tcx = tl/10, tty = tl%10;
  int c0 = tcx*32, r0 = tty*32;
  int tid = threadIdx.x;
  int tx = tid & 31, rg = tid >> 5;
  {
    const ushort* fb = F1bf + (size_t)ci*NPIX;
    for (int idx = tid; idx < 34*34; idx += 256){
      int lr = idx/34, lc = idx%34;
      int h = r0 - 1 + lr, w = c0 - 1 + lc;
      rect[lr][lc] = (h >= 0 && h < HP && w >= 0 && w < HP) ? bf2f(fb[(size_t)h*HP + w]) : 0.0f;
    }
    __syncthreads();
    #pragma unroll
    for (int kk=0; kk<4; kk++){
      int lrow = rg + 8*kk;
      int h = r0 + lrow, w = c0 + tx;
      ushort o;
      if (h >= HP || w >= HP) o = 0;
      else if (h==0 || h==HP-1 || w==0 || w==HP-1) o = f2bf(1.0f);
      else {
        float mv = fmaxf(fmaxf(rect[lrow][tx],   rect[lrow][tx+1]),   rect[lrow][tx+2]);
        mv = fmaxf(mv, fmaxf(fmaxf(rect[lrow+1][tx], rect[lrow+1][tx+1]), rect[lrow+1][tx+2]));
        mv = fmaxf(mv, fmaxf(fmaxf(rect[lrow+2][tx], rect[lrow+2][tx+1]), rect[lrow+2][tx+2]));
        o = f2bf(mv);
      }
      BF0[(size_t)ci*NPB + (size_t)h*BSTR + w] = o;
    }
    __syncthreads();
  }
  const float* xb = XP + (size_t)ci*NPIX;
  const float* yb = F2 + (size_t)ci*NPIX;
  for (int idx = tid; idx < 34*34; idx += 256){
    int lr = idx/34, lc = idx%34;
    int h = r0 - 1 + lr, w = c0 - 1 + lc;
    float v = 0.0f;
    if (h >= 0 && h < HP && w >= 0 && w < HP){
      float xv = xb[(size_t)h*HP + w];
      float off = yb[(size_t)h*HP + w] - xv - cm[ci*HP + w];
      v = xv + fmaxf(off, 0.0f);
    }
    rect[lr][lc] = v;
  }
  __syncthreads();
  float xs_acc = 0.0f, as_acc = 0.0f;
  #pragma unroll
  for (int kk=0; kk<4; kk++){
    int lrow = rg + 8*kk;
    int h = r0 + lrow, w = c0 + tx;
    bool vpix = (h < HP && w < HP);
    ushort o;
    if (!vpix) o = 0;
    else {
      float xv = rect[lrow+1][tx+1];
      X1[(size_t)ci*NPIX + (size_t)h*HP + w] = xv;
      xs_acc += xv;
      if (h==0 || h==HP-1 || w==0 || w==HP-1){
        o = f2bf(1.0f);
        as_acc += 1.0f;
      } else {
        float av = (rect[lrow][tx]   + rect[lrow][tx+1]   + rect[lrow][tx+2])
                 + (rect[lrow+1][tx] + rect[lrow+1][tx+1] + rect[lrow+1][tx+2])
                 + (rect[lrow+2][tx] + rect[lrow+2][tx+1] + rect[lrow+2][tx+2]);
        o = f2bf(av*(1.0f/9.0f));
        as_acc += bf2f(o);
      }
    }
    BF2[(size_t)ci*NPB + (size_t)h*BSTR + w] = o;
  }
  cr2[0][rg][tx] = xs_acc;
  cr2[1][rg][tx] = as_acc;
  __syncthreads();
  if (tid < 32){
    float xs = 0.0f, as = 0.0f;
    #pragma unroll
    for (int g=0; g<8; g++){ xs += cr2[0][g][tid]; as += cr2[1][g][tid]; }
    x1part[((size_t)ci*10 + tty)*320 + c0 + tid] = xs;
    a2part[((size_t)ci*10 + tty)*320 + c0 + tid] = as;
  }
}

// ---- invrect (unchanged) ---------------------------------------------------
__global__ __launch_bounds__(256) void fb_invrect_k(const float* __restrict__ F1,
    ushort* __restrict__ An, const float* __restrict__ X1,
    const float* __restrict__ F2, const float* __restrict__ cm,
    ushort* __restrict__ An2){
  bool second = (blockIdx.x >= PBLK);
  int p = (second ? blockIdx.x - PBLK : (int)blockIdx.x)*256 + threadIdx.x;
  if (p >= PTOT) return;
  int h = p / BSTR, w = p % BSTR;
  ushort* dst = second ? An2 : An;
  if (h >= HP || w >= HP){
    #pragma unroll
    for (int c=0;c<C30;c++) dst[(size_t)c*NPB+p] = 0;
    return;
  }
  int pd = h*HP + w;
  float v[C30];
  float ss = 0.0f;
  if (!second){
    #pragma unroll
    for (int c=0;c<C30;c++){ v[c] = F1[(size_t)c*NPIX+pd]; ss = fmaf(v[c],v[c],ss); }
  } else {
    #pragma unroll
    for (int c=0;c<C30;c++){
      float xv = X1[(size_t)c*NPIX + pd];
      float off = F2[(size_t)c*NPIX + pd] - xv - cm[c*HP + w];
      float vv = xv + fmaxf(off, 0.0f);
      v[c] = vv;
      ss = fmaf(vv, vv, ss);
    }
  }
  float n = sqrtf(2.0f*ss);
  float inv = 1.0f / fmaxf(n, 1e-12f);
  #pragma unroll
  for (int c=0;c<C30;c++) dst[(size_t)c*NPB+p] = f2bf(v[c]*inv);
}

// ---- paired mm absred: 1D grid 750, XCD-swizzled ---------------------------
__global__ __launch_bounds__(256) void fb_mmabs_k(const ushort* __restrict__ Aop,
    const ushort* __restrict__ Adil, const ushort* __restrict__ BT,
    const float* __restrict__ XPop, double* __restrict__ part){
  __shared__ ushort As1[64*72];
  __shared__ ushort As2[64*72];
  __shared__ ushort BsP[64*72];
  __shared__ ushort BsN[64*72];
  __shared__ double red[256];
  int wg = xcd_swz(blockIdx.x, 750);
  int bx = wg % 5, by = (wg/5) % 5, ch = wg/25;
  int lin = by*5 + bx;
  mm_abs_pair_body(Aop + (size_t)ch*NPB, Adil + (size_t)ch*NPB, BT + (size_t)ch*NPB,
                   XPop + (size_t)ch*NPIX,
                   &part[(size_t)ch*25 + lin],
                   &part[(size_t)(C30+ch)*25 + lin],
                   bx, by, threadIdx.x, As1, As2, BsP, BsN, red);
}

__global__ void fb_finalize_k(const double* __restrict__ part,
                              const float* __restrict__ base, float* __restrict__ out){
  __shared__ double s0[256], s1[256];
  int tid = threadIdx.x;
  double l0=0.0, l1=0.0;
  for (int i=tid;i<750;i+=256){ l0 += part[i]; l1 += part[750+i]; }
  s0[tid]=l0; s1[tid]=l1; __syncthreads();
  for (int s=128;s>0;s>>=1){ if (tid<s){ s0[tid]+=s0[tid+s]; s1[tid]+=s1[tid+s]; } __syncthreads(); }
  if (tid==0) out[0] = (float)(fabs(2.0*(s0[0]-s1[0])) + (double)base[0]);
}

extern "C" void kernel_launch(void* const* d_in, const int* in_sizes, int n_in,
                              void* d_out, int out_size, void* d_ws, size_t ws_size,
                              hipStream_t stream){
  const float* logits = (const float*)d_in[0];
  const float* base   = (const float*)d_in[1];
  float* out = (float*)d_out;

  char* ws = (char*)d_ws;
  size_t off = 0;
  auto alloc = [&](size_t bytes)->char*{
    char* p = ws + off; off = (off + bytes + 255) & ~(size_t)255; return p;
  };
  double* part    = (double*)alloc(1500*sizeof(double));
  float*  cm      = (float*) alloc((size_t)C30*HP*sizeof(float));
  float*  xpart   = (float*) alloc((size_t)C30*10*320*sizeof(float));
  float*  apart   = (float*) alloc((size_t)C30*10*320*sizeof(float));
  float*  x1part  = (float*) alloc((size_t)C30*10*320*sizeof(float));
  float*  a2part  = (float*) alloc((size_t)C30*10*320*sizeof(float));
  float*  XP      = (float*) alloc((size_t)TOT*sizeof(float));
  ushort* BF0     = (ushort*)alloc((size_t)C30*NPB*sizeof(ushort));
  ushort* BFT     = (ushort*)alloc((size_t)C30*NPB*sizeof(ushort));
  ushort* BF1     = (ushort*)alloc((size_t)C30*NPB*sizeof(ushort));
  ushort* BF2     = (ushort*)alloc((size_t)C30*NPB*sizeof(ushort));
  ushort* F1bf    = (ushort*)alloc((size_t)TOT*sizeof(ushort));   // opening C1 (bf16 dense)
  float*  F1      = (float*) alloc((size_t)TOT*sizeof(float));    // opening O2 (fp32)
  float*  F2      = (float*) alloc((size_t)TOT*sizeof(float));
  float*  X1      = (float*) alloc((size_t)TOT*sizeof(float));
  (void)ws_size; (void)in_sizes; (void)n_in; (void)out_size;

  dim3 baGrid(100, 10);
  dim3 prGrid(100, C30);

  fb_buildall_k<<<baGrid,256,0,stream>>>(logits, XP, BFT, BF1, BF2, xpart, apart);
  fb_mm_k<1><<<780,256,0,stream>>>(BF1, BF2, BFT, F1bf, F2, XP, apart, xpart, cm);
  fb_poolrect_k<<<prGrid,256,0,stream>>>(F1bf, BF0, XP, F2, cm, X1, BF2, x1part, a2part);
  fb_mm_k<0><<<780,256,0,stream>>>(BF0, BF2, BFT, F1, F2, XP, a2part, x1part, cm);
  fb_invrect_k<<<820,256,0,stream>>>(F1, BF1, X1, F2, cm, BF0);
  fb_mmabs_k<<<750,256,0,stream>>>(BF1, BF0, BFT, XP, part);
  fb_finalize_k<<<1,256,0,stream>>>(part, base, out);
}